// Round 15
// baseline (113.608 us; speedup 1.0000x reference)
//
#include <hip/hip_runtime.h>
#include <hip/hip_bf16.h>

typedef __attribute__((ext_vector_type(8))) short bf16x8;
typedef __attribute__((ext_vector_type(4))) float f32x4;
typedef __attribute__((ext_vector_type(4))) unsigned int u32x4;
typedef __attribute__((ext_vector_type(2))) unsigned int u32x2;

__device__ __forceinline__ float b2f(unsigned short u) {
  unsigned int x = ((unsigned int)u) << 16;
  float f;
  __builtin_memcpy(&f, &x, 4);
  return f;
}
__device__ __forceinline__ unsigned short f2b(float f) {
  __hip_bfloat16 h = __float2bfloat16(f);
  unsigned short u;
  __builtin_memcpy(&u, &h, 2);
  return u;
}

// ---------------------------------------------------------------------------
// merged prep kernel, grid dim3(16,16,18), 256 thr (R9-proven, L3-resident)
// ---------------------------------------------------------------------------
__global__ __launch_bounds__(256) void prep_all(
    const float* __restrict__ X, const float* __restrict__ adj,
    const float* __restrict__ W, unsigned short* __restrict__ XT,
    unsigned short* __restrict__ AJ, unsigned short* __restrict__ WT,
    float theta) {
  const int z = blockIdx.z;
  const int t = threadIdx.x;
  const int r0 = blockIdx.y * 64, c0 = blockIdx.x * 64;

  if (z == 17) {  // adj convert
#pragma unroll
    for (int p = 0; p < 4; ++p) {
      const int id = t + 256 * p;
      const int r = id >> 4, c4 = (id & 15) * 4;
      f32x4 v = *(const f32x4*)(adj + (size_t)(r0 + r) * 1024 + (c0 + c4));
      unsigned short o[4];
#pragma unroll
      for (int j = 0; j < 4; ++j) o[j] = f2b(v[j]);
      u32x2 pk;
      __builtin_memcpy(&pk, o, 8);
      *(u32x2*)(AJ + (size_t)(r0 + r) * 1024 + (c0 + c4)) = pk;
    }
    return;
  }

  if (z == 16) {  // W' = theta*W^T + (1-theta)*I
    __shared__ float tile[64][65];
#pragma unroll
    for (int p = 0; p < 4; ++p) {
      const int id = t + 256 * p;
      const int r = id >> 4, c4 = (id & 15) * 4;
      f32x4 v = *(const f32x4*)(W + (size_t)(r0 + r) * 1024 + (c0 + c4));
#pragma unroll
      for (int j = 0; j < 4; ++j) tile[r][c4 + j] = v[j];
    }
    __syncthreads();
#pragma unroll
    for (int p = 0; p < 2; ++p) {
      const int id = t + 256 * p;
      const int oc = id >> 3, cr8 = (id & 7) * 8;
      u32x4 v;
      unsigned short* pv = (unsigned short*)&v;
#pragma unroll
      for (int j = 0; j < 8; ++j) {
        const int o = c0 + oc, f = r0 + cr8 + j;
        float val = theta * tile[cr8 + j][oc] + (o == f ? (1.0f - theta) : 0.f);
        pv[j] = f2b(val);
      }
      *(u32x4*)(WT + (size_t)(c0 + oc) * 1024 + (r0 + cr8)) = v;
    }
    return;
  }

  // z < 16: X transpose-convert
  __shared__ unsigned short tile[64][68];
  const float* s = X + (size_t)z * 1024 * 1024;
  unsigned short* d = XT + (size_t)z * 1024 * 1024;
#pragma unroll
  for (int p = 0; p < 4; ++p) {
    const int id = t + 256 * p;
    const int r = id >> 4, c4 = (id & 15) * 4;
    f32x4 v = *(const f32x4*)(s + (size_t)(r0 + r) * 1024 + (c0 + c4));
#pragma unroll
    for (int j = 0; j < 4; ++j) tile[r][c4 + j] = f2b(v[j]);
  }
  __syncthreads();
#pragma unroll
  for (int p = 0; p < 2; ++p) {
    const int id = t + 256 * p;
    const int oc = id >> 3, cr8 = (id & 7) * 8;
    u32x4 v;
    unsigned short* pv = (unsigned short*)&v;
#pragma unroll
    for (int j = 0; j < 8; ++j) pv[j] = tile[cr8 + j][oc];
    *(u32x4*)(d + (size_t)(c0 + oc) * 1024 + (r0 + cr8)) = v;
  }
}

// ---------------------------------------------------------------------------
// GEMM1 (new): S = bf16( 0.9*(adj·X') + 0.1*h0 ), M=1024, N=16384 batch cols.
// BM=256 x BN=128 tiles, K-step 64, SINGLE-buffer 48KB LDS, 2-barrier m97
// loop, 512 blocks -> 2 blocks/CU (launch_bounds(512,4) caps VGPR at 128).
// Tail (scalar h0-fused epilogue) overlaps the co-resident block's K-loop.
// ---------------------------------------------------------------------------
__global__ __launch_bounds__(512, 4) void gemm1(
    const unsigned short* __restrict__ A, const unsigned short* __restrict__ BT,
    const float* __restrict__ E, unsigned short* __restrict__ Cq,
    float c0, float c1) {
  constexpr int NT = 16;
  constexpr size_t NF = 1024ull * 1024ull;
  __shared__ unsigned short Abuf[256 * 64];  // 32 KB
  __shared__ unsigned short Bbuf[128 * 64];  // 16 KB
  const int bid = blockIdx.x;                     // 512 blocks
  const int nid = (bid & 7) * 64 + (bid >> 3);    // XCD chunk remap (bijective)
  const size_t m0 = (size_t)(nid >> 7) * 256;     // 4 m-panels (adj rows)
  const size_t n0 = (size_t)(nid & 127) * 128;    // 128 n-panels (batch cols)
  const int t = threadIdx.x, lane = t & 63, wv = t >> 6;
  const int wm = (wv >> 1) * 64, wn = (wv & 1) * 64;  // 4m x 2n waves

  f32x4 acc[4][4];
#pragma unroll
  for (int i = 0; i < 4; ++i)
#pragma unroll
    for (int j = 0; j < 4; ++j) acc[i][j] = (f32x4){0.f, 0.f, 0.f, 0.f};

  for (int tt = 0; tt < NT; ++tt) {
    const int k0 = tt * 64;
    __syncthreads();  // previous iteration's readers done
    // stage A: 256 rows x 64 cols (4 passes x 512 thr x 16B)
#pragma unroll
    for (int l = 0; l < 4; ++l) {
      const int id = l * 512 + t;
      const int rl = id >> 3, c = id & 7;
      const int gc = (c ^ (rl & 7)) << 3;
      const unsigned short* g = A + (m0 + rl) * 1024 + k0 + gc;
      __builtin_amdgcn_global_load_lds(
          (const __attribute__((address_space(1))) unsigned int*)g,
          (__attribute__((address_space(3))) unsigned int*)(Abuf + id * 8),
          16, 0, 0);
    }
    // stage B: 128 rows x 64 cols (2 passes)
#pragma unroll
    for (int l = 0; l < 2; ++l) {
      const int id = l * 512 + t;
      const int rl = id >> 3, c = id & 7;
      const int gc = (c ^ (rl & 7)) << 3;
      const unsigned short* g = BT + (n0 + rl) * 1024 + k0 + gc;
      __builtin_amdgcn_global_load_lds(
          (const __attribute__((address_space(1))) unsigned int*)g,
          (__attribute__((address_space(3))) unsigned int*)(Bbuf + id * 8),
          16, 0, 0);
    }
    asm volatile("s_waitcnt vmcnt(0)" ::: "memory");
    __syncthreads();

    // B fragments (keep live), A per-mi (transient) -> low VGPR
    bf16x8 br[4][2];
#pragma unroll
    for (int nj = 0; nj < 4; ++nj)
#pragma unroll
      for (int kk = 0; kk < 2; ++kk) {
        const int row = wn + nj * 16 + (lane & 15);
        const int ch = ((kk * 4 + (lane >> 4)) ^ (row & 7)) << 3;
        br[nj][kk] = *(const bf16x8*)(Bbuf + row * 64 + ch);
      }
#pragma unroll
    for (int mi = 0; mi < 4; ++mi) {
      bf16x8 ar[2];
#pragma unroll
      for (int kk = 0; kk < 2; ++kk) {
        const int row = wm + mi * 16 + (lane & 15);
        const int ch = ((kk * 4 + (lane >> 4)) ^ (row & 7)) << 3;
        ar[kk] = *(const bf16x8*)(Abuf + row * 64 + ch);
      }
#pragma unroll
      for (int nj = 0; nj < 4; ++nj)
#pragma unroll
        for (int kk = 0; kk < 2; ++kk)
          acc[mi][nj] = __builtin_amdgcn_mfma_f32_16x16x32_bf16(
              ar[kk], br[nj][kk], acc[mi][nj], 0, 0, 0);
    }
  }

  // scalar h0-fused epilogue (R4-proven math); overlapped by co-resident block
  const size_t base = (n0 >> 10) * NF + (n0 & 1023) + m0 * 1024;
  const float* Eb = E + base;
  unsigned short* Cb = Cq + base;
#pragma unroll
  for (int mi = 0; mi < 4; ++mi) {
#pragma unroll
    for (int r = 0; r < 4; ++r) {
      const int lrow = wm + mi * 16 + (lane >> 4) * 4 + r;
#pragma unroll
      for (int nj = 0; nj < 4; ++nj) {
        const int lcol = wn + nj * 16 + (lane & 15);
        const float v =
            c0 * acc[mi][nj][r] + c1 * Eb[(size_t)lrow * 1024 + lcol];
        Cb[(size_t)lrow * 1024 + lcol] = f2b(v);
      }
    }
  }
}

// ---------------------------------------------------------------------------
// GEMM2 helpers + kernel (R14/R9-proven, ~38us) — unchanged
// ---------------------------------------------------------------------------
__device__ __forceinline__ void stage_tile16(unsigned short* ldsbase,
                                             const unsigned short* __restrict__ gbase,
                                             size_t rowbase, int half, int k0,
                                             int t, int wv) {
#pragma unroll
  for (int l = 0; l < 2; ++l) {
    const int id = l * 512 + t;
    const int rl = id >> 3, c = id & 7;
    const int gc = (c ^ (rl & 7)) << 3;
    const unsigned short* g = gbase + (rowbase + half * 128 + rl) * 1024 + k0 + gc;
    unsigned short* dst = ldsbase + half * 8192 + (l * 512 + wv * 64) * 8;
    __builtin_amdgcn_global_load_lds(
        (const __attribute__((address_space(1))) unsigned int*)g,
        (__attribute__((address_space(3))) unsigned int*)dst, 16, 0, 0);
  }
}

#define LOAD_A(MH)                                                     \
  {                                                                    \
    const unsigned short* Ard = lds[rd * 2 + 0];                       \
    _Pragma("unroll") for (int mi = 0; mi < 4; ++mi)                   \
        _Pragma("unroll") for (int kk = 0; kk < 2; ++kk) {             \
      const int row = wm + (MH)*64 + mi * 16 + (lane & 15);            \
      const int ch = ((kk * 4 + (lane >> 4)) ^ (row & 7)) << 3;        \
      areg[mi][kk] = *(const bf16x8*)(Ard + row * 64 + ch);            \
    }                                                                  \
  }
#define LOAD_B(NH, BR)                                                 \
  {                                                                    \
    const unsigned short* Brd = lds[rd * 2 + 1];                       \
    _Pragma("unroll") for (int nj = 0; nj < 2; ++nj)                   \
        _Pragma("unroll") for (int kk = 0; kk < 2; ++kk) {             \
      const int row = wn + (NH)*32 + nj * 16 + (lane & 15);            \
      const int ch = ((kk * 4 + (lane >> 4)) ^ (row & 7)) << 3;        \
      BR[nj][kk] = *(const bf16x8*)(Brd + row * 64 + ch);              \
    }                                                                  \
  }
#define MFMA_Q(MH, NH, BR)                                             \
  do {                                                                 \
    __builtin_amdgcn_s_setprio(1);                                     \
    _Pragma("unroll") for (int mi = 0; mi < 4; ++mi)                   \
        _Pragma("unroll") for (int nj = 0; nj < 2; ++nj)               \
            _Pragma("unroll") for (int kk = 0; kk < 2; ++kk)           \
        acc[(MH)*4 + mi][(NH)*2 + nj] =                                \
        __builtin_amdgcn_mfma_f32_16x16x32_bf16(                       \
            areg[mi][kk], BR[nj][kk], acc[(MH)*4 + mi][(NH)*2 + nj],   \
            0, 0, 0);                                                  \
    __builtin_amdgcn_s_setprio(0);                                     \
  } while (0)
#define LGKM0                                          \
  asm volatile("s_waitcnt lgkmcnt(0)" ::: "memory");   \
  __builtin_amdgcn_sched_barrier(0)
#define BAR __builtin_amdgcn_s_barrier()

__global__ __launch_bounds__(512, 2) void gemm2(
    const unsigned short* __restrict__ A, const unsigned short* __restrict__ BT,
    float* __restrict__ Co) {
  constexpr int NT = 16;
  __shared__ unsigned short lds[4][16384];
  const int bid = blockIdx.x;
  const int nid = (bid & 7) * 32 + (bid >> 3);
  const size_t m0 = (size_t)(nid >> 2) * 256, n0 = (size_t)(nid & 3) * 256;
  const int t = threadIdx.x, lane = t & 63, wv = t >> 6;
  const int wm = (wv >> 2) * 128, wn = (wv & 3) * 64;

  f32x4 acc[8][4];
#pragma unroll
  for (int i = 0; i < 8; ++i)
#pragma unroll
    for (int j = 0; j < 4; ++j) acc[i][j] = (f32x4){0.f, 0.f, 0.f, 0.f};
  bf16x8 areg[4][2], b0r[2][2], b1r[2][2];

  stage_tile16(lds[0], A, m0, 0, 0, t, wv);
  stage_tile16(lds[0], A, m0, 1, 0, t, wv);
  stage_tile16(lds[1], BT, n0, 0, 0, t, wv);
  stage_tile16(lds[1], BT, n0, 1, 0, t, wv);
  stage_tile16(lds[3], BT, n0, 0, 64, t, wv);
  stage_tile16(lds[2], A, m0, 0, 64, t, wv);
  asm volatile("s_waitcnt vmcnt(4)" ::: "memory");
  BAR;

  for (int tt = 0; tt < NT; ++tt) {
    const int rd = tt & 1, wr = rd ^ 1;
    LOAD_A(0);
    LOAD_B(0, b0r);
    if (tt + 1 < NT) stage_tile16(lds[wr * 2 + 1], BT, n0, 1, (tt + 1) * 64, t, wv);
    BAR; LGKM0; MFMA_Q(0, 0, b0r); BAR;
    LOAD_B(1, b1r);
    if (tt + 1 < NT) stage_tile16(lds[wr * 2 + 0], A, m0, 1, (tt + 1) * 64, t, wv);
    BAR; LGKM0; MFMA_Q(0, 1, b1r); BAR;
    LOAD_A(1);
    if (tt + 2 < NT) stage_tile16(lds[rd * 2 + 1], BT, n0, 0, (tt + 2) * 64, t, wv);
    BAR; LGKM0; MFMA_Q(1, 1, b1r); BAR;
    if (tt + 2 < NT) stage_tile16(lds[rd * 2 + 0], A, m0, 0, (tt + 2) * 64, t, wv);
    BAR; LGKM0; MFMA_Q(1, 0, b0r);
    asm volatile("s_waitcnt vmcnt(4)" ::: "memory");
    BAR;
  }

  const size_t base = m0 * 1024 + n0;
  float* ldsF = (float*)lds;
#pragma unroll
  for (int MH = 0; MH < 2; ++MH) {
    __syncthreads();
    if ((wv >> 2) == MH) {
      const int q = lane >> 4;
#pragma unroll
      for (int mi = 0; mi < 8; ++mi)
#pragma unroll
        for (int nj = 0; nj < 4; ++nj)
#pragma unroll
          for (int r = 0; r < 4; ++r) {
            const int row = mi * 16 + q * 4 + r;
            const int col = (wn + nj * 16 + (lane & 15)) ^ (q << 4);
            ldsF[row * 256 + col] = acc[mi][nj][r];
          }
    }
    __syncthreads();
#pragma unroll 4
    for (int it = 0; it < 16; ++it) {
      const int chunk = it * 512 + t;
      const int row = chunk >> 6;
      const int c4 = (chunk & 63) * 4;
      const int sc4 = c4 ^ (((row >> 2) & 3) << 4);
      const f32x4 s = *(const f32x4*)(ldsF + row * 256 + sc4);
      *(f32x4*)(Co + base + (size_t)(MH * 128 + row) * 1024 + c4) = s;
    }
  }
}

#undef LOAD_A
#undef LOAD_B
#undef MFMA_Q
#undef LGKM0
#undef BAR

// ---------------------------------------------------------------------------
// out = (0.9*(adj·X) + 0.1*h0) · (theta*W + (1-theta)*I)
// theta = log(1.5) (static: lamda=0.5, l=1 in setup_inputs)
// ---------------------------------------------------------------------------
extern "C" void kernel_launch(void* const* d_in, const int* in_sizes, int n_in,
                              void* d_out, int out_size, void* d_ws,
                              size_t ws_size, hipStream_t stream) {
  const float* X = (const float*)d_in[0];    // [16,1024,1024] f32
  const float* adj = (const float*)d_in[1];  // [1024,1024] f32
  const float* h0 = (const float*)d_in[2];   // [16,1024,1024] f32
  const float* W = (const float*)d_in[3];    // [1024,1024] f32
  float* out = (float*)d_out;                // [16,1024,1024] f32

  const size_t NF = 1024ull * 1024ull;
  unsigned short* XT = (unsigned short*)d_ws;  // 16*NF bf16: X' transposed
  unsigned short* WT = XT + 16 * NF;           // NF bf16: theta*W^T+(1-theta)I
  unsigned short* AJ = WT + NF;                // NF bf16
  unsigned short* S = AJ + NF;                 // 16*NF bf16

  const float theta = 0.405465108f;  // log(1.5)

  prep_all<<<dim3(16, 16, 18), 256, 0, stream>>>(X, adj, W, XT, AJ, WT, theta);

  // S = bf16( 0.9*(adj · X') + 0.1*h0 )  (256x128 tiles, 2 blocks/CU)
  gemm1<<<dim3(512), 512, 0, stream>>>(AJ, XT, h0, S, 0.9f, 0.1f);
  // out = f32( S · W'^T )  (256^2 8-phase)
  gemm2<<<dim3(256), 512, 0, stream>>>(S, WT, out);
}

// Round 16
// 104.681 us; speedup vs baseline: 1.0853x; 1.0853x over previous
//
#include <hip/hip_runtime.h>
#include <hip/hip_bf16.h>

typedef __attribute__((ext_vector_type(8))) short bf16x8;
typedef __attribute__((ext_vector_type(4))) float f32x4;
typedef __attribute__((ext_vector_type(4))) unsigned int u32x4;
typedef __attribute__((ext_vector_type(2))) unsigned int u32x2;

__device__ __forceinline__ float b2f(unsigned short u) {
  unsigned int x = ((unsigned int)u) << 16;
  float f;
  __builtin_memcpy(&f, &x, 4);
  return f;
}
__device__ __forceinline__ unsigned short f2b(float f) {
  __hip_bfloat16 h = __float2bfloat16(f);
  unsigned short u;
  __builtin_memcpy(&u, &h, 2);
  return u;
}

// ---------------------------------------------------------------------------
// merged prep kernel, grid dim3(16,16,18), 256 thr (R9-proven, L3-resident)
// ---------------------------------------------------------------------------
__global__ __launch_bounds__(256) void prep_all(
    const float* __restrict__ X, const float* __restrict__ adj,
    const float* __restrict__ W, unsigned short* __restrict__ XT,
    unsigned short* __restrict__ AJ, unsigned short* __restrict__ WT,
    float theta) {
  const int z = blockIdx.z;
  const int t = threadIdx.x;
  const int r0 = blockIdx.y * 64, c0 = blockIdx.x * 64;

  if (z == 17) {  // adj convert
#pragma unroll
    for (int p = 0; p < 4; ++p) {
      const int id = t + 256 * p;
      const int r = id >> 4, c4 = (id & 15) * 4;
      f32x4 v = *(const f32x4*)(adj + (size_t)(r0 + r) * 1024 + (c0 + c4));
      unsigned short o[4];
#pragma unroll
      for (int j = 0; j < 4; ++j) o[j] = f2b(v[j]);
      u32x2 pk;
      __builtin_memcpy(&pk, o, 8);
      *(u32x2*)(AJ + (size_t)(r0 + r) * 1024 + (c0 + c4)) = pk;
    }
    return;
  }

  if (z == 16) {  // W' = theta*W^T + (1-theta)*I
    __shared__ float tile[64][65];
#pragma unroll
    for (int p = 0; p < 4; ++p) {
      const int id = t + 256 * p;
      const int r = id >> 4, c4 = (id & 15) * 4;
      f32x4 v = *(const f32x4*)(W + (size_t)(r0 + r) * 1024 + (c0 + c4));
#pragma unroll
      for (int j = 0; j < 4; ++j) tile[r][c4 + j] = v[j];
    }
    __syncthreads();
#pragma unroll
    for (int p = 0; p < 2; ++p) {
      const int id = t + 256 * p;
      const int oc = id >> 3, cr8 = (id & 7) * 8;
      u32x4 v;
      unsigned short* pv = (unsigned short*)&v;
#pragma unroll
      for (int j = 0; j < 8; ++j) {
        const int o = c0 + oc, f = r0 + cr8 + j;
        float val = theta * tile[cr8 + j][oc] + (o == f ? (1.0f - theta) : 0.f);
        pv[j] = f2b(val);
      }
      *(u32x4*)(WT + (size_t)(c0 + oc) * 1024 + (r0 + cr8)) = v;
    }
    return;
  }

  // z < 16: X transpose-convert
  __shared__ unsigned short tile[64][68];
  const float* s = X + (size_t)z * 1024 * 1024;
  unsigned short* d = XT + (size_t)z * 1024 * 1024;
#pragma unroll
  for (int p = 0; p < 4; ++p) {
    const int id = t + 256 * p;
    const int r = id >> 4, c4 = (id & 15) * 4;
    f32x4 v = *(const f32x4*)(s + (size_t)(r0 + r) * 1024 + (c0 + c4));
#pragma unroll
    for (int j = 0; j < 4; ++j) tile[r][c4 + j] = f2b(v[j]);
  }
  __syncthreads();
#pragma unroll
  for (int p = 0; p < 2; ++p) {
    const int id = t + 256 * p;
    const int oc = id >> 3, cr8 = (id & 7) * 8;
    u32x4 v;
    unsigned short* pv = (unsigned short*)&v;
#pragma unroll
    for (int j = 0; j < 8; ++j) pv[j] = tile[cr8 + j][oc];
    *(u32x4*)(d + (size_t)(c0 + oc) * 1024 + (r0 + cr8)) = v;
  }
}

// ---------------------------------------------------------------------------
// shared helpers for the 256x256 8-phase GEMMs (K = 1024)
// ---------------------------------------------------------------------------
__device__ __forceinline__ void stage_tile16(unsigned short* ldsbase,
                                             const unsigned short* __restrict__ gbase,
                                             size_t rowbase, int half, int k0,
                                             int t, int wv) {
#pragma unroll
  for (int l = 0; l < 2; ++l) {
    const int id = l * 512 + t;
    const int rl = id >> 3, c = id & 7;
    const int gc = (c ^ (rl & 7)) << 3;  // pre-swizzled global chunk
    const unsigned short* g = gbase + (rowbase + half * 128 + rl) * 1024 + k0 + gc;
    unsigned short* dst = ldsbase + half * 8192 + (l * 512 + wv * 64) * 8;
    __builtin_amdgcn_global_load_lds(
        (const __attribute__((address_space(1))) unsigned int*)g,
        (__attribute__((address_space(3))) unsigned int*)dst, 16, 0, 0);
  }
}

#define LOAD_A(MH)                                                     \
  {                                                                    \
    const unsigned short* Ard = lds[rd * 2 + 0];                       \
    _Pragma("unroll") for (int mi = 0; mi < 4; ++mi)                   \
        _Pragma("unroll") for (int kk = 0; kk < 2; ++kk) {             \
      const int row = wm + (MH)*64 + mi * 16 + (lane & 15);            \
      const int ch = ((kk * 4 + (lane >> 4)) ^ (row & 7)) << 3;        \
      areg[mi][kk] = *(const bf16x8*)(Ard + row * 64 + ch);            \
    }                                                                  \
  }
#define LOAD_B(NH, BR)                                                 \
  {                                                                    \
    const unsigned short* Brd = lds[rd * 2 + 1];                       \
    _Pragma("unroll") for (int nj = 0; nj < 2; ++nj)                   \
        _Pragma("unroll") for (int kk = 0; kk < 2; ++kk) {             \
      const int row = wn + (NH)*32 + nj * 16 + (lane & 15);            \
      const int ch = ((kk * 4 + (lane >> 4)) ^ (row & 7)) << 3;        \
      BR[nj][kk] = *(const bf16x8*)(Brd + row * 64 + ch);              \
    }                                                                  \
  }
#define MFMA_Q(MH, NH, BR)                                             \
  do {                                                                 \
    __builtin_amdgcn_s_setprio(1);                                     \
    _Pragma("unroll") for (int mi = 0; mi < 4; ++mi)                   \
        _Pragma("unroll") for (int nj = 0; nj < 2; ++nj)               \
            _Pragma("unroll") for (int kk = 0; kk < 2; ++kk)           \
        acc[(MH)*4 + mi][(NH)*2 + nj] =                                \
        __builtin_amdgcn_mfma_f32_16x16x32_bf16(                       \
            areg[mi][kk], BR[nj][kk], acc[(MH)*4 + mi][(NH)*2 + nj],   \
            0, 0, 0);                                                  \
    __builtin_amdgcn_s_setprio(0);                                     \
  } while (0)
#define LGKM0                                          \
  asm volatile("s_waitcnt lgkmcnt(0)" ::: "memory");   \
  __builtin_amdgcn_sched_barrier(0)
#define BAR __builtin_amdgcn_s_barrier()

#define GEMM_KLOOP                                                            \
  for (int tt = 0; tt < NT; ++tt) {                                           \
    const int rd = tt & 1, wr = rd ^ 1;                                       \
    LOAD_A(0);                                                                \
    LOAD_B(0, b0r);                                                           \
    if (tt + 1 < NT)                                                          \
      stage_tile16(lds[wr * 2 + 1], BT, n0, 1, (tt + 1) * 64, t, wv);         \
    BAR; LGKM0; MFMA_Q(0, 0, b0r); BAR;                                       \
    LOAD_B(1, b1r);                                                           \
    if (tt + 1 < NT)                                                          \
      stage_tile16(lds[wr * 2 + 0], A, m0, 1, (tt + 1) * 64, t, wv);          \
    BAR; LGKM0; MFMA_Q(0, 1, b1r); BAR;                                       \
    LOAD_A(1);                                                                \
    if (tt + 2 < NT)                                                          \
      stage_tile16(lds[rd * 2 + 1], BT, n0, 0, (tt + 2) * 64, t, wv);         \
    BAR; LGKM0; MFMA_Q(1, 1, b1r); BAR;                                       \
    if (tt + 2 < NT)                                                          \
      stage_tile16(lds[rd * 2 + 0], A, m0, 0, (tt + 2) * 64, t, wv);          \
    BAR; LGKM0; MFMA_Q(1, 0, b0r);                                            \
    asm volatile("s_waitcnt vmcnt(4)" ::: "memory");                          \
    BAR;                                                                      \
  }

#define GEMM_PROLOGUE                                                         \
  stage_tile16(lds[0], A, m0, 0, 0, t, wv);                                   \
  stage_tile16(lds[0], A, m0, 1, 0, t, wv);                                   \
  stage_tile16(lds[1], BT, n0, 0, 0, t, wv);                                  \
  stage_tile16(lds[1], BT, n0, 1, 0, t, wv);                                  \
  stage_tile16(lds[3], BT, n0, 0, 64, t, wv);                                 \
  stage_tile16(lds[2], A, m0, 0, 64, t, wv);                                  \
  asm volatile("s_waitcnt vmcnt(4)" ::: "memory");                            \
  BAR;

// ---------------------------------------------------------------------------
// GEMM1: S = bf16( 0.9*(adj · X') + 0.1*h0 ),  M=1024, N=16384 (batch cols).
// XCD-grouped tile map: m0=(nid&3), n0=(nid>>2) -> the 4 blocks sharing an
// XT column-panel are dispatch-adjacent on ONE XCD (L2 temporal reuse),
// matching gemm2's (faster) mapping style. Epilogue: bulk early-issue h0.
// ---------------------------------------------------------------------------
__global__ __launch_bounds__(512, 2) void gemm1(
    const unsigned short* __restrict__ A, const unsigned short* __restrict__ BT,
    const float* __restrict__ E, unsigned short* __restrict__ Cq,
    float c0, float c1) {
  constexpr int NT = 16;
  constexpr size_t NF = 1024ull * 1024ull;
  __shared__ unsigned short lds[4][16384];
  const int bid = blockIdx.x;
  const int nid = (bid & 7) * 32 + (bid >> 3);  // XCD chunk remap
  const size_t m0 = (size_t)(nid & 3) * 256;    // all 4 m-tiles per XCD group
  const size_t n0 = (size_t)(nid >> 2) * 256;   // 8 XT panels per XCD
  const int t = threadIdx.x, lane = t & 63, wv = t >> 6;
  const int wm = (wv >> 2) * 128, wn = (wv & 3) * 64;

  f32x4 acc[8][4];
#pragma unroll
  for (int i = 0; i < 8; ++i)
#pragma unroll
    for (int j = 0; j < 4; ++j) acc[i][j] = (f32x4){0.f, 0.f, 0.f, 0.f};
  bf16x8 areg[4][2], b0r[2][2], b1r[2][2];

  GEMM_PROLOGUE
  GEMM_KLOOP

  // epilogue (batch-column mapping)
  const size_t base = (n0 >> 10) * NF + (n0 & 1023) + m0 * 1024;
  const float* Eb = E + base;
  unsigned short* Cb = Cq + base;
  float* ldsF = (float*)lds;
#pragma unroll
  for (int MH = 0; MH < 2; ++MH) {
    __syncthreads();  // LDS buffer safe to overwrite
    // bulk-issue h0 reads: 8 chunks x 8 f32 (2 f32x4 each); retire under dump
    f32x4 hva[8], hvb[8];
#pragma unroll
    for (int it = 0; it < 8; ++it) {
      const int chunk = it * 512 + t;
      const int row = chunk >> 5;
      const int c8 = (chunk & 31) * 8;
      const size_t go = (size_t)(MH * 128 + row) * 1024 + c8;
      hva[it] = *(const f32x4*)(Eb + go);
      hvb[it] = *(const f32x4*)(Eb + go + 4);
    }
    if ((wv >> 2) == MH) {
      const int q = lane >> 4;
#pragma unroll
      for (int mi = 0; mi < 8; ++mi)
#pragma unroll
        for (int nj = 0; nj < 4; ++nj)
#pragma unroll
          for (int r = 0; r < 4; ++r) {
            const int row = mi * 16 + q * 4 + r;
            const int col = (wn + nj * 16 + (lane & 15)) ^ (q << 4);
            ldsF[row * 256 + col] = acc[mi][nj][r];
          }
    }
    __syncthreads();  // drains ds_writes AND h0 loads
#pragma unroll
    for (int it = 0; it < 8; ++it) {
      const int chunk = it * 512 + t;
      const int row = chunk >> 5;
      const int c8 = (chunk & 31) * 8;
      const int sc8 = c8 ^ (((row >> 2) & 3) << 4);  // bits 4-5 XOR, 8-safe
      const f32x4 sa = *(const f32x4*)(ldsF + row * 256 + sc8);
      const f32x4 sb = *(const f32x4*)(ldsF + row * 256 + sc8 + 4);
      u32x4 ov;
#pragma unroll
      for (int w = 0; w < 4; ++w) {
        const float s0 = (w < 2) ? sa[2 * w] : sb[2 * w - 4];
        const float s1 = (w < 2) ? sa[2 * w + 1] : sb[2 * w - 3];
        const float h0v = (w < 2) ? hva[it][2 * w] : hvb[it][2 * w - 4];
        const float h1v = (w < 2) ? hva[it][2 * w + 1] : hvb[it][2 * w - 3];
        ov[w] = (unsigned int)f2b(c0 * s0 + c1 * h0v) |
                ((unsigned int)f2b(c0 * s1 + c1 * h1v) << 16);
      }
      *(u32x4*)(Cb + (size_t)(MH * 128 + row) * 1024 + c8) = ov;
    }
  }
}

// ---------------------------------------------------------------------------
// GEMM2: out = f32( S · W'^T ),  M=16384, N=1024. Write-only, LDS-exchange
// epilogue (R9-proven, ~38us). Mapping already XCD-grouped (m-major).
// ---------------------------------------------------------------------------
__global__ __launch_bounds__(512, 2) void gemm2(
    const unsigned short* __restrict__ A, const unsigned short* __restrict__ BT,
    float* __restrict__ Co) {
  constexpr int NT = 16;
  __shared__ unsigned short lds[4][16384];
  const int bid = blockIdx.x;
  const int nid = (bid & 7) * 32 + (bid >> 3);
  const size_t m0 = (size_t)(nid >> 2) * 256, n0 = (size_t)(nid & 3) * 256;
  const int t = threadIdx.x, lane = t & 63, wv = t >> 6;
  const int wm = (wv >> 2) * 128, wn = (wv & 3) * 64;

  f32x4 acc[8][4];
#pragma unroll
  for (int i = 0; i < 8; ++i)
#pragma unroll
    for (int j = 0; j < 4; ++j) acc[i][j] = (f32x4){0.f, 0.f, 0.f, 0.f};
  bf16x8 areg[4][2], b0r[2][2], b1r[2][2];

  GEMM_PROLOGUE
  GEMM_KLOOP

  const size_t base = m0 * 1024 + n0;
  float* ldsF = (float*)lds;
#pragma unroll
  for (int MH = 0; MH < 2; ++MH) {
    __syncthreads();
    if ((wv >> 2) == MH) {
      const int q = lane >> 4;
#pragma unroll
      for (int mi = 0; mi < 8; ++mi)
#pragma unroll
        for (int nj = 0; nj < 4; ++nj)
#pragma unroll
          for (int r = 0; r < 4; ++r) {
            const int row = mi * 16 + q * 4 + r;
            const int col = (wn + nj * 16 + (lane & 15)) ^ (q << 4);
            ldsF[row * 256 + col] = acc[mi][nj][r];
          }
    }
    __syncthreads();
#pragma unroll 4
    for (int it = 0; it < 16; ++it) {
      const int chunk = it * 512 + t;
      const int row = chunk >> 6;
      const int c4 = (chunk & 63) * 4;
      const int sc4 = c4 ^ (((row >> 2) & 3) << 4);
      const f32x4 s = *(const f32x4*)(ldsF + row * 256 + sc4);
      *(f32x4*)(Co + base + (size_t)(MH * 128 + row) * 1024 + c4) = s;
    }
  }
}

#undef LOAD_A
#undef LOAD_B
#undef MFMA_Q
#undef LGKM0
#undef BAR
#undef GEMM_KLOOP
#undef GEMM_PROLOGUE

// ---------------------------------------------------------------------------
// out = (0.9*(adj·X) + 0.1*h0) · (theta*W + (1-theta)*I)
// theta = log(1.5) (static: lamda=0.5, l=1 in setup_inputs)
// ---------------------------------------------------------------------------
extern "C" void kernel_launch(void* const* d_in, const int* in_sizes, int n_in,
                              void* d_out, int out_size, void* d_ws,
                              size_t ws_size, hipStream_t stream) {
  const float* X = (const float*)d_in[0];    // [16,1024,1024] f32
  const float* adj = (const float*)d_in[1];  // [1024,1024] f32
  const float* h0 = (const float*)d_in[2];   // [16,1024,1024] f32
  const float* W = (const float*)d_in[3];    // [1024,1024] f32
  float* out = (float*)d_out;                // [16,1024,1024] f32

  const size_t NF = 1024ull * 1024ull;
  unsigned short* XT = (unsigned short*)d_ws;  // 16*NF bf16: X' transposed
  unsigned short* WT = XT + 16 * NF;           // NF bf16: theta*W^T+(1-theta)I
  unsigned short* AJ = WT + NF;                // NF bf16
  unsigned short* S = AJ + NF;                 // 16*NF bf16

  const float theta = 0.405465108f;  // log(1.5)

  prep_all<<<dim3(16, 16, 18), 256, 0, stream>>>(X, adj, W, XT, AJ, WT, theta);

  // S = bf16( 0.9*(adj · X') + 0.1*h0 )  (XCD-grouped XT reuse)
  gemm1<<<dim3(256), 512, 0, stream>>>(AJ, XT, h0, S, 0.9f, 0.1f);
  // out = f32( S · W'^T )
  gemm2<<<dim3(256), 512, 0, stream>>>(S, WT, out);
}